// Round 4
// baseline (263.073 us; speedup 1.0000x reference)
//
#include <hip/hip_runtime.h>
#include <hip/hip_bf16.h>

// ---------------- problem constants ----------------
#define B_N   8
#define S_N   4096
#define D_N   256          // DQK == DV
#define QBLK  64           // q rows per block (32 per wave; waves 0/1 = team0, 2/3 = team1)
#define KVBLK 32           // keys per tile per team
#define SCALE 0.0625f      // 1/sqrt(256), folded into Q prepass

typedef __attribute__((ext_vector_type(8)))  short bf16x8;
typedef __attribute__((ext_vector_type(16))) float f32x16;

// ---------------- async global->LDS (16B/lane, wave-uniform LDS base) -------
__device__ __forceinline__ void async16(const char* g, char* l) {
  __builtin_amdgcn_global_load_lds(
      (const __attribute__((address_space(1))) void*)g,
      (__attribute__((address_space(3))) void*)l, 16, 0, 0);
}

__device__ __forceinline__ unsigned cvt_pk_bf16(float lo, float hi) {
  unsigned r;
  asm("v_cvt_pk_bf16_f32 %0, %1, %2" : "=v"(r) : "v"(lo), "v"(hi));
  return r;
}
// upper 32 lanes of a <-> lower 32 lanes of b
__device__ __forceinline__ void swap32(unsigned& a, unsigned& b) {
  asm("v_permlane32_swap_b32 %0, %1" : "+v"(a), "+v"(b));
}
// full-wave combine of per-half partials (opaque asm keeps a,b in distinct regs)
__device__ __forceinline__ float xhalf_max(float x) {
  float a = x, b = x;
  asm("" : "+v"(b));
  asm("v_permlane32_swap_b32 %0, %1" : "+v"(a), "+v"(b));
  return fmaxf(a, b);
}
__device__ __forceinline__ float xhalf_add(float x) {
  float a = x, b = x;
  asm("" : "+v"(b));
  asm("v_permlane32_swap_b32 %0, %1" : "+v"(a), "+v"(b));
  return a + b;
}

// ---------------- prepass: NCHW -> (B,S,D) bf16 with pos add (+scale) -------
__global__ void prep_qk(const float* __restrict__ src, const float* __restrict__ pos,
                        __hip_bfloat16* __restrict__ dst, float mul) {
  __shared__ float tile[64][65];
  const int b  = blockIdx.z;
  const int s0 = blockIdx.x * 64;
  const int c0 = blockIdx.y * 64;
  const int t  = threadIdx.x;
  const int x  = t & 63;
  const int y4 = t >> 6;
  const float* sp = src + ((size_t)b * D_N + c0) * S_N + s0;
#pragma unroll
  for (int i = 0; i < 16; ++i) {
    int c = y4 + i * 4;
    tile[c][x] = sp[(size_t)c * S_N + x];
  }
  __syncthreads();
  __hip_bfloat16* dp = dst + ((size_t)b * S_N + s0) * D_N + c0;
  const float* pp = pos + (size_t)s0 * D_N + c0;
#pragma unroll
  for (int i = 0; i < 16; ++i) {
    int s = y4 + i * 4;
    float v = (tile[x][s] + pp[(size_t)s * D_N + x]) * mul;
    dp[(size_t)s * D_N + x] = __float2bfloat16(v);
  }
}

// V: (B,D,S) fp32 -> (B,D,S) bf16 cast
struct alignas(8) bf4 { __hip_bfloat16 a, b, c, d; };
__global__ void prep_v(const float* __restrict__ src, __hip_bfloat16* __restrict__ dst) {
  size_t i = (size_t)blockIdx.x * blockDim.x + threadIdx.x;
  float4 v = reinterpret_cast<const float4*>(src)[i];
  bf4 o { __float2bfloat16(v.x), __float2bfloat16(v.y),
          __float2bfloat16(v.z), __float2bfloat16(v.w) };
  *reinterpret_cast<bf4*>(dst + i * 4) = o;
}

// ---------------- flash attention, KV-split teams, 32x32 MFMA ---------------
// LDS per block (66560 B):
//   team tm at lds + tm*32768:
//     [0,16K)  K tile: 32 keys x 512B, 16B slots XOR-swizzled by (row&7)<<4
//     [16K,32K) V tile: packed [64 rows x 256B]; row r holds d=4r..4r+3 (64B each,
//               32 keys x bf16); 16B slot s stored at s ^ (r&15)
//   [65536, 66560) merge scratch: per-wave (m,l) float2 x 32 q
#define LDS_BYTES 66560

__global__ __launch_bounds__(256, 2) void attn_kernel(
    const __hip_bfloat16* __restrict__ Qb, const __hip_bfloat16* __restrict__ Kb,
    const __hip_bfloat16* __restrict__ Vtb, float* __restrict__ out) {
  __shared__ __align__(16) char lds[LDS_BYTES];

  const int tid  = threadIdx.x;
  const int wave = tid >> 6;
  const int team = wave >> 1;        // 0: keys [0,2048), 1: keys [2048,4096)
  const int w    = wave & 1;         // q sub-tile within block
  const int lane = tid & 63;
  const int l31  = lane & 31;
  const int h    = lane >> 5;
  const int l7   = lane & 7;

  // XCD swizzle: hw block i -> XCD i%8; all of batch b on XCD b
  const int lin   = blockIdx.x;          // 0..511
  const int b     = lin & 7;
  const int qtile = lin >> 3;            // 0..63
  const int q0    = qtile * QBLK + w * 32;
  const int K0    = team * (S_N / 2);

  // ---- Q fragments resident in registers (B-operand layout) ----
  bf16x8 qf[16];
  {
    const __hip_bfloat16* qp = Qb + ((size_t)b * S_N + q0 + l31) * D_N + h * 8;
#pragma unroll
    for (int kc = 0; kc < 16; ++kc)
      qf[kc] = *reinterpret_cast<const bf16x8*>(qp + kc * 16);
  }

  // ---- accumulators: O^T (8 d-frags of 32), online-softmax state ----
  f32x16 o[8];
#pragma unroll
  for (int df = 0; df < 8; ++df)
#pragma unroll
    for (int r = 0; r < 16; ++r) o[df][r] = 0.f;
  float m_ = -1e30f, l_ = 0.f;

  char* Klds = lds + team * 32768;
  char* Vlds = Klds + 16384;
  const char* kgbase = reinterpret_cast<const char*>(Kb  + (size_t)b * S_N * D_N);
  const char* vgbase = reinterpret_cast<const char*>(Vtb + (size_t)b * D_N * S_N);

  for (int t = 0; t < (S_N / 2) / KVBLK; ++t) {     // 64 tiles per team
    const int key0 = K0 + t * KVBLK;
    __syncthreads();   // previous tile fully consumed (block-wide)
    {
      // K tile: 32 rows x 512B = 16 x 1KB segments, 8 per wave
      const char* kt = kgbase + (size_t)key0 * (D_N * 2);
#pragma unroll
      for (int i = 0; i < 8; ++i) {
        int c    = w * 8 + i;
        int T    = c * 1024 + lane * 16;
        int row  = T >> 9;
        int colb = T & 511;
        async16(kt + row * 512 + (colb ^ ((row & 7) << 4)), Klds + c * 1024);
      }
      // V tile: packed [64 x 256B], slot-swizzled; 16 x 1KB segments, 8 per wave
#pragma unroll
      for (int i = 0; i < 8; ++i) {
        int c  = w * 8 + i;
        int T  = c * 1024 + lane * 16;
        int r  = T >> 8;                  // packed row (4 d's)
        int sp = (T >> 4) & 15;           // physical 16B slot
        int sl = sp ^ (r & 15);           // logical slot
        int d  = r * 4 + (sl >> 2);
        async16(vgbase + (size_t)d * (S_N * 2) + key0 * 2 + (sl & 3) * 16,
                Vlds + c * 1024);
      }
    }
    __syncthreads();   // staged data visible

    // ---- QK^T (swapped): S^T[key][q] = mfma(A=K, B=Q), one 32x32 C-frag ----
    f32x16 se;
#pragma unroll
    for (int r = 0; r < 16; ++r) se[r] = 0.f;
    {
      const char* kr = Klds + l31 * 512;
      const int swz = l7 << 4;
      __builtin_amdgcn_s_setprio(1);
#pragma unroll
      for (int kc = 0; kc < 16; ++kc) {
        bf16x8 kf = *reinterpret_cast<const bf16x8*>(kr + ((kc * 32 + h * 16) ^ swz));
        se = __builtin_amdgcn_mfma_f32_32x32x16_bf16(kf, qf[kc], se, 0, 0, 0);
      }
      __builtin_amdgcn_s_setprio(0);
    }

    // ---- online softmax (lane-local + one cross-half combine) ----
    float t8[8];
#pragma unroll
    for (int i = 0; i < 8; ++i) t8[i] = fmaxf(se[i], se[i + 8]);
    float pm = fmaxf(fmaxf(fmaxf(t8[0], t8[1]), fmaxf(t8[2], t8[3])),
                     fmaxf(fmaxf(t8[4], t8[5]), fmaxf(t8[6], t8[7])));
    float pmax = xhalf_max(pm);

    if (!__all(pmax <= m_ + 8.f)) {        // defer-max
      float mn = fmaxf(m_, pmax);
      float al = __expf(m_ - mn);
      m_ = mn;
      l_ *= al;
#pragma unroll
      for (int df = 0; df < 8; ++df)
#pragma unroll
        for (int r = 0; r < 16; ++r) o[df][r] *= al;
    }
#pragma unroll
    for (int r = 0; r < 16; ++r) se[r] = __expf(se[r] - m_);
    float s8[8];
#pragma unroll
    for (int i = 0; i < 8; ++i) s8[i] = se[i] + se[i + 8];
    float rs = ((s8[0] + s8[1]) + (s8[2] + s8[3])) + ((s8[4] + s8[5]) + (s8[6] + s8[7]));
    l_ += xhalf_add(rs);

    // ---- P -> bf16 B-fragments in-register (cvt_pk + permlane32_swap) ----
    union U8 { unsigned u[4]; bf16x8 v; };
    U8 pb[2];
    {
      unsigned u0 = cvt_pk_bf16(se[0],  se[1]);
      unsigned v0 = cvt_pk_bf16(se[4],  se[5]);
      swap32(u0, v0);
      unsigned u1 = cvt_pk_bf16(se[2],  se[3]);
      unsigned v1 = cvt_pk_bf16(se[6],  se[7]);
      swap32(u1, v1);
      pb[0].u[0] = u0; pb[0].u[1] = u1; pb[0].u[2] = v0; pb[0].u[3] = v1;
      unsigned u2 = cvt_pk_bf16(se[8],  se[9]);
      unsigned v2 = cvt_pk_bf16(se[12], se[13]);
      swap32(u2, v2);
      unsigned u3 = cvt_pk_bf16(se[10], se[11]);
      unsigned v3 = cvt_pk_bf16(se[14], se[15]);
      swap32(u3, v3);
      pb[1].u[0] = u2; pb[1].u[1] = u3; pb[1].u[2] = v2; pb[1].u[3] = v3;
    }

    // ---- PV (swapped): O^T[d][q] += mfma(A=V^T, B=P) ----
    __builtin_amdgcn_s_setprio(1);
#pragma unroll
    for (int df = 0; df < 8; ++df) {
      const int rr = df * 8 + (l31 >> 2);            // packed V row
      const char* vr = Vlds + rr * 256;
      const int rx = ((df & 1) * 8) + (l31 >> 2);    // rr & 15
#pragma unroll
      for (int kf = 0; kf < 2; ++kf) {
        int sl = (l31 & 3) * 4 + kf * 2 + h;
        int sp = sl ^ rx;
        bf16x8 vf = *reinterpret_cast<const bf16x8*>(vr + sp * 16);
        o[df] = __builtin_amdgcn_mfma_f32_32x32x16_bf16(vf, pb[kf].v, o[df], 0, 0, 0);
      }
    }
    __builtin_amdgcn_s_setprio(0);
  }

  // ---- merge the two teams' online-softmax states, then store ----
  float2* mlb = reinterpret_cast<float2*>(lds + 65536);
  if (h == 0) mlb[wave * 32 + l31] = make_float2(m_, l_);
  __syncthreads();                       // all loops done; (m,l) published
  float2 pml = mlb[(wave ^ 2) * 32 + l31];
  float mstar = fmaxf(m_, pml.x);
  float c     = __expf(m_ - mstar);

  if (team == 1) {                       // publish scaled partial O
    float* obuf = reinterpret_cast<float*>(lds + w * 32768);
#pragma unroll
    for (int df = 0; df < 8; ++df)
#pragma unroll
      for (int r = 0; r < 16; ++r) {
        int d = df * 32 + (r & 3) + 8 * (r >> 2) + 4 * h;
        obuf[d * 32 + l31] = o[df][r] * c;
      }
  }
  __syncthreads();
  if (team == 0) {                       // combine + normalize + store
    float cp    = __expf(pml.x - mstar);
    float lstar = c * l_ + pml.y;        // pml.y already includes... (raw l1)
    lstar = c * l_ + cp * pml.y;
    float inv   = 1.0f / lstar;
    const float* obuf = reinterpret_cast<const float*>(lds + w * 32768);
    float* ob = out + (size_t)b * D_N * S_N + q0 + l31;
#pragma unroll
    for (int df = 0; df < 8; ++df)
#pragma unroll
      for (int r = 0; r < 16; ++r) {
        int d = df * 32 + (r & 3) + 8 * (r >> 2) + 4 * h;
        ob[(size_t)d * S_N] = (o[df][r] * c + obuf[d * 32 + l31]) * inv;
      }
  }
}

// ---------------- launch ----------------
extern "C" void kernel_launch(void* const* d_in, const int* in_sizes, int n_in,
                              void* d_out, int out_size, void* d_ws, size_t ws_size,
                              hipStream_t stream) {
  const float* queries = (const float*)d_in[0];
  const float* keys    = (const float*)d_in[1];
  const float* values  = (const float*)d_in[2];
  const float* q_pos   = (const float*)d_in[3];
  const float* k_pos   = (const float*)d_in[4];
  float* out = (float*)d_out;

  const size_t per = (size_t)B_N * S_N * D_N;
  __hip_bfloat16* Qb  = (__hip_bfloat16*)d_ws;
  __hip_bfloat16* Kb  = Qb + per;
  __hip_bfloat16* Vtb = Kb + per;          // 50.3 MB of ws total

  prep_qk<<<dim3(S_N / 64, D_N / 64, B_N), 256, 0, stream>>>(queries, q_pos, Qb, SCALE);
  prep_qk<<<dim3(S_N / 64, D_N / 64, B_N), 256, 0, stream>>>(keys,    k_pos, Kb, 1.0f);
  prep_v <<<dim3((unsigned)(per / 4 / 256)), 256, 0, stream>>>(values, Vtb);
  attn_kernel<<<dim3((S_N / QBLK) * B_N), 256, 0, stream>>>(Qb, Kb, Vtb, out);
}